// Round 9
// baseline (273.243 us; speedup 1.0000x reference)
//
#include <hip/hip_runtime.h>
#include <hip/hip_bf16.h>

#define NB 2
#define NL 2048
#define NH 12
#define ND 64
#define NEWTON 6
#define WV 8            // waves per block (attn)
#define TPW 16          // key-tiles per wave = 128/WV

typedef __bf16 bf16x8 __attribute__((ext_vector_type(8)));
typedef float f32x4 __attribute__((ext_vector_type(4)));
typedef float f32x2 __attribute__((ext_vector_type(2)));

// DPP row_ror reductions within each 16-lane row.
#define ROR_ADD(v, n)                                                         \
  (v) += __int_as_float(__builtin_amdgcn_update_dpp(                          \
      0, __float_as_int(v), 0x120 + (n), 0xF, 0xF, true))
#define ROR_MAX(v, n)                                                         \
  (v) = fmaxf((v), __int_as_float(__builtin_amdgcn_update_dpp(                \
                  0, __float_as_int(v), 0x120 + (n), 0xF, 0xF, true)))

__device__ __forceinline__ void split_bf16(float f, __bf16& hi, __bf16& lo) {
  __bf16 h = (__bf16)f;
  hi = h;
  lo = (__bf16)(f - (float)h);
}

// Quad reciprocal: given pairs a,b, produce ra=(1/a.x,1/a.y), rb=(1/b.x,1/b.y)
// with ONE v_rcp_f32 + 5 muls (all pairable). Rel err ~3e-7.
__device__ __forceinline__ void quad_rcp(f32x2 a, f32x2 b, f32x2& ra, f32x2& rb) {
  f32x2 P2 = a * b;                       // (a.x b.x, a.y b.y)
  float z = __builtin_amdgcn_rcpf(P2.x * P2.y);
  f32x2 wsw = z * __builtin_shufflevector(P2, P2, 1, 0);  // (1/(a.x b.x), 1/(a.y b.y))
  ra = wsw * b;
  rb = wsw * a;
}

// ---- prep: block = (b, kt16, head-group of 4). 768 blocks, 256 thr, 33 KB LDS.
// Kp[bh][kt(128)][chunk(2)][lane(64)][8] ; Vp[bh][pi(64)][n(4)][lane(64)][8]
__global__ __launch_bounds__(256) void prep(
    const float* __restrict__ kg, const float* __restrict__ vg,
    __bf16* __restrict__ kp_hi, __bf16* __restrict__ kp_lo,
    __bf16* __restrict__ vp_hi, __bf16* __restrict__ vp_lo) {
  __shared__ __align__(16) float kv[2][16][260];  // [K/V][key][4 heads x 64 d]
  const int blk = blockIdx.x;
  const int hg = blk % 3;
  const int kt = (blk / 3) & 127;
  const int b = blk / 384;
  const int t = threadIdx.x;
  const int w = t >> 6;           // wave 0..3 == local head
  const int lane = t & 63;
  const int quad = lane >> 4;
  const int l16 = lane & 15;

#pragma unroll
  for (int i = 0; i < 4; ++i) {
    const int f = i * 1024 + t * 4;
    const int key = f >> 8;
    const int rem = f & 255;
    const size_t src =
        (size_t)(b * NL + kt * 16 + key) * (NH * ND) + hg * 256 + rem;
    *(f32x4*)(&kv[0][key][rem]) = *(const f32x4*)(kg + src);
    *(f32x4*)(&kv[1][key][rem]) = *(const f32x4*)(vg + src);
  }
  __syncthreads();

  const int h = hg * 4 + w;

  // ---- K pack ----
  {
    const float* p = &kv[0][l16][w * 64 + quad * 8];
    f32x4 a0 = *(const f32x4*)(p);
    f32x4 a1 = *(const f32x4*)(p + 4);
    f32x4 a2 = *(const f32x4*)(p + 32);
    f32x4 a3 = *(const f32x4*)(p + 36);
    bf16x8 h0, l0, h1, l1;
#pragma unroll
    for (int j = 0; j < 4; ++j) {
      __bf16 hb, lb;
      split_bf16(a0[j], hb, lb); h0[j] = hb;     l0[j] = lb;
      split_bf16(a1[j], hb, lb); h0[4 + j] = hb; l0[4 + j] = lb;
      split_bf16(a2[j], hb, lb); h1[j] = hb;     l1[j] = lb;
      split_bf16(a3[j], hb, lb); h1[4 + j] = hb; l1[4 + j] = lb;
    }
    const size_t basek =
        ((size_t)((b * NH + h) * 128 + kt) * 2) * 512 + lane * 8;
    *(bf16x8*)(kp_hi + basek) = h0;
    *(bf16x8*)(kp_lo + basek) = l0;
    *(bf16x8*)(kp_hi + basek + 512) = h1;
    *(bf16x8*)(kp_lo + basek + 512) = l1;
  }

  // ---- V pack ----
  {
    const int halfsel = (kt >> 3) & 1;
    const int pi = (kt >> 4) * 8 + (kt & 7);
    const int q2 = quad & 1;
    const int nhalf = quad >> 1;
    const int qdst = 2 * halfsel + q2;
#pragma unroll
    for (int nn = 0; nn < 2; ++nn) {
      const int n = nhalf * 2 + nn;
      bf16x8 hv, lv;
#pragma unroll
      for (int j = 0; j < 8; ++j) {
        __bf16 hb, lb;
        split_bf16(kv[1][q2 * 8 + j][w * 64 + n * 16 + l16], hb, lb);
        hv[j] = hb;
        lv[j] = lb;
      }
      const size_t off =
          ((((size_t)(b * NH + h) * 64 + pi) * 4 + n) * 64 + qdst * 16 + l16) * 8;
      *(bf16x8*)(vp_hi + off) = hv;
      *(bf16x8*)(vp_lo + off) = lv;
    }
  }
}

// ---------------- main fused attention-poly kernel ----------------
__launch_bounds__(512, 4)
__global__ void attn_poly(const float* __restrict__ qg,
                          const __bf16* __restrict__ kp_hi,
                          const __bf16* __restrict__ kp_lo,
                          const __bf16* __restrict__ vp_hi,
                          const __bf16* __restrict__ vp_lo,
                          float* __restrict__ outg) {
  __shared__ __align__(16) float ex[WV][16][68];
  __shared__ float redmax[WV][17];     // +1 pad: kills 8-way read conflicts
  __shared__ f32x2 redq[2][WV][17];    // (Sum y^-2, Sum y^-3), padded row

  const int tid = threadIdx.x;
  const int w = tid >> 6;
  const int lane = tid & 63;
  const int quad = lane >> 4;
  const int l16 = lane & 15;

  const int blk = blockIdx.x;
  const int qt = blk & 127;
  const int bh = blk >> 7;
  const int h = bh % NH;
  const int b = bh / NH;
  const int qbase = qt * 16;

  // ---- Q fragments: fp32 * 0.125 -> bf16 hi/lo ----
  bf16x8 qhi0, qlo0, qhi1, qlo1;
  {
    const float* qp = qg + ((b * NL + qbase + l16) * NH + h) * ND + quad * 8;
    f32x4 a0 = *(const f32x4*)(qp);
    f32x4 a1 = *(const f32x4*)(qp + 4);
    f32x4 a2 = *(const f32x4*)(qp + 32);
    f32x4 a3 = *(const f32x4*)(qp + 36);
#pragma unroll
    for (int j = 0; j < 4; ++j) {
      __bf16 hb, lb;
      split_bf16(a0[j] * 0.125f, hb, lb); qhi0[j] = hb;     qlo0[j] = lb;
      split_bf16(a1[j] * 0.125f, hb, lb); qhi0[4 + j] = hb; qlo0[4 + j] = lb;
      split_bf16(a2[j] * 0.125f, hb, lb); qhi1[j] = hb;     qlo1[j] = lb;
      split_bf16(a3[j] * 0.125f, hb, lb); qhi1[4 + j] = hb; qlo1[4 + j] = lb;
    }
  }

  // ---- phase 1: S = (Q/8) Kt ; sc2[t][j] = rows (quad*4+2j, +2j+1), col l16 ----
  f32x2 sc2[TPW][2];   // scores, read-only after this phase
  {
    const __bf16* kbh = kp_hi + (size_t)bh * 131072;
    const __bf16* kbl = kp_lo + (size_t)bh * 131072;
#pragma unroll
    for (int t = 0; t < TPW; ++t) {
      const int ktile = w + WV * t;
      const size_t o = (size_t)ktile * 1024 + lane * 8;
      bf16x8 khi0 = *(const bf16x8*)(kbh + o);
      bf16x8 khi1 = *(const bf16x8*)(kbh + o + 512);
      bf16x8 klo0 = *(const bf16x8*)(kbl + o);
      bf16x8 klo1 = *(const bf16x8*)(kbl + o + 512);
      f32x4 acc = {0.f, 0.f, 0.f, 0.f};
      acc = __builtin_amdgcn_mfma_f32_16x16x32_bf16(qhi0, khi0, acc, 0, 0, 0);
      acc = __builtin_amdgcn_mfma_f32_16x16x32_bf16(qhi1, khi1, acc, 0, 0, 0);
      acc = __builtin_amdgcn_mfma_f32_16x16x32_bf16(qhi0, klo0, acc, 0, 0, 0);
      acc = __builtin_amdgcn_mfma_f32_16x16x32_bf16(qhi1, klo1, acc, 0, 0, 0);
      acc = __builtin_amdgcn_mfma_f32_16x16x32_bf16(qlo0, khi0, acc, 0, 0, 0);
      acc = __builtin_amdgcn_mfma_f32_16x16x32_bf16(qlo1, khi1, acc, 0, 0, 0);
      sc2[t][0] = __builtin_shufflevector(acc, acc, 0, 1);
      sc2[t][1] = __builtin_shufflevector(acc, acc, 2, 3);
    }
  }

  // ---- phase 2: row max -> negc[j] = -c0 pairs (= max + 1) ----
  f32x2 negc[2];
  {
    f32x2 mx2[2] = {sc2[0][0], sc2[0][1]};
#pragma unroll
    for (int t = 1; t < TPW; ++t) {
#pragma unroll
      for (int j = 0; j < 2; ++j) {
        mx2[j].x = fmaxf(mx2[j].x, sc2[t][j].x);
        mx2[j].y = fmaxf(mx2[j].y, sc2[t][j].y);
      }
    }
#pragma unroll
    for (int j = 0; j < 2; ++j) {
      ROR_MAX(mx2[j].x, 8); ROR_MAX(mx2[j].x, 4); ROR_MAX(mx2[j].x, 2); ROR_MAX(mx2[j].x, 1);
      ROR_MAX(mx2[j].y, 8); ROR_MAX(mx2[j].y, 4); ROR_MAX(mx2[j].y, 2); ROR_MAX(mx2[j].y, 1);
    }
    if (l16 < 4) {
      float v = (l16 == 0) ? mx2[0].x : (l16 == 1) ? mx2[0].y
              : (l16 == 2) ? mx2[1].x : mx2[1].y;
      redmax[w][quad * 4 + l16] = v;
    }
    __syncthreads();
#pragma unroll
    for (int r = 0; r < 4; ++r) {
      float m = redmax[l16 & 7][quad * 4 + r];
      ROR_MAX(m, 4); ROR_MAX(m, 2); ROR_MAX(m, 1);
      ((float*)negc)[r] = m + 1.0f;            // -c0 = max + 1
    }
  }

  // ---- phase 3: Newton x6 on c (negc += step); quad-packed reciprocals ----
  for (int it = 0; it < NEWTON; ++it) {
    const int par = it & 1;
    f32x2 ps2[2] = {{0.f, 0.f}, {0.f, 0.f}};
    f32x2 psd2[2] = {{0.f, 0.f}, {0.f, 0.f}};
#pragma unroll
    for (int t = 0; t < TPW; ++t) {
      f32x2 a = negc[0] - sc2[t][0];           // y pairs, y >= 1 along path
      f32x2 bb = negc[1] - sc2[t][1];
      f32x2 ra, rb;
      quad_rcp(a, bb, ra, rb);                 // 1 rcp per 4 elements
      f32x2 r2a = ra * ra;
      f32x2 r2b = rb * rb;
      ps2[0] += r2a;
      ps2[1] += r2b;
      psd2[0] += r2a * ra;
      psd2[1] += r2b * rb;
    }
#pragma unroll
    for (int j = 0; j < 2; ++j) {
      ROR_ADD(ps2[j].x, 8);  ROR_ADD(ps2[j].x, 4);  ROR_ADD(ps2[j].x, 2);  ROR_ADD(ps2[j].x, 1);
      ROR_ADD(ps2[j].y, 8);  ROR_ADD(ps2[j].y, 4);  ROR_ADD(ps2[j].y, 2);  ROR_ADD(ps2[j].y, 1);
      ROR_ADD(psd2[j].x, 8); ROR_ADD(psd2[j].x, 4); ROR_ADD(psd2[j].x, 2); ROR_ADD(psd2[j].x, 1);
      ROR_ADD(psd2[j].y, 8); ROR_ADD(psd2[j].y, 4); ROR_ADD(psd2[j].y, 2); ROR_ADD(psd2[j].y, 1);
    }
    if (l16 < 4) {
      float a = (l16 == 0) ? ps2[0].x : (l16 == 1) ? ps2[0].y
              : (l16 == 2) ? ps2[1].x : ps2[1].y;
      float d = (l16 == 0) ? psd2[0].x : (l16 == 1) ? psd2[0].y
              : (l16 == 2) ? psd2[1].x : psd2[1].y;
      redq[par][w][quad * 4 + l16] = f32x2{a, d};
    }
    __syncthreads();
#pragma unroll
    for (int r = 0; r < 4; ++r) {
      f32x2 v = redq[par][l16 & 7][quad * 4 + r];
      ROR_ADD(v.x, 4); ROR_ADD(v.x, 2); ROR_ADD(v.x, 1);
      ROR_ADD(v.y, 4); ROR_ADD(v.y, 2); ROR_ADD(v.y, 1);
      // c -= (ps-1)/(2 psd + eps)  =>  negc += same
      ((float*)negc)[r] +=
          (v.x - 1.0f) * __builtin_amdgcn_rcpf(2.0f * v.y + 1e-8f);
    }
  }

  // ---- phase 5: weights = 1/y^2 on the fly; O_partial = W * (Vhi + Vlo) ----
  f32x4 oacc[4];
#pragma unroll
  for (int n = 0; n < 4; ++n) oacc[n] = (f32x4){0.f, 0.f, 0.f, 0.f};
  float* myslab = &ex[w][0][0];
  const __bf16* vpbh = vp_hi + (size_t)bh * 131072;
  const __bf16* vpbl = vp_lo + (size_t)bh * 131072;
#pragma unroll
  for (int p = 0; p < 8; ++p) {
#pragma unroll
    for (int ts = 0; ts < 2; ++ts) {
      const int t = 2 * p + ts;
      f32x2 a = negc[0] - sc2[t][0];
      f32x2 bb = negc[1] - sc2[t][1];
      f32x2 ra, rb;
      quad_rcp(a, bb, ra, rb);
      f32x2 wa = ra * ra;
      f32x2 wb = rb * rb;
      myslab[(quad * 4 + 0) * 68 + ts * 16 + l16] = wa.x;
      myslab[(quad * 4 + 1) * 68 + ts * 16 + l16] = wa.y;
      myslab[(quad * 4 + 2) * 68 + ts * 16 + l16] = wb.x;
      myslab[(quad * 4 + 3) * 68 + ts * 16 + l16] = wb.y;
    }
    asm volatile("s_waitcnt lgkmcnt(0)" ::: "memory");  // wave-internal exchange
    f32x4 w0 = *(const f32x4*)(myslab + l16 * 68 + quad * 8);
    f32x4 w1 = *(const f32x4*)(myslab + l16 * 68 + quad * 8 + 4);
    bf16x8 aw;
#pragma unroll
    for (int j = 0; j < 4; ++j) {
      aw[j] = (__bf16)w0[j];
      aw[4 + j] = (__bf16)w1[j];
    }
    const size_t vo = ((size_t)(p * 8 + w) * 4) * 512 + lane * 8;
#pragma unroll
    for (int n = 0; n < 4; ++n) {
      bf16x8 bhv = *(const bf16x8*)(vpbh + vo + n * 512);
      bf16x8 blv = *(const bf16x8*)(vpbl + vo + n * 512);
      oacc[n] = __builtin_amdgcn_mfma_f32_16x16x32_bf16(aw, bhv, oacc[n], 0, 0, 0);
      oacc[n] = __builtin_amdgcn_mfma_f32_16x16x32_bf16(aw, blv, oacc[n], 0, 0, 0);
    }
    asm volatile("s_waitcnt lgkmcnt(0)" ::: "memory");
  }

  // ---- phase 6: reduce partials across waves, write global ----
#pragma unroll
  for (int n = 0; n < 4; ++n)
#pragma unroll
    for (int r = 0; r < 4; ++r)
      ex[w][quad * 4 + r][n * 16 + l16] = oacc[n][r];
  __syncthreads();
  {
    const int row = 2 * w + (lane >> 5);
    const int d = lane & 31;
    float v0 = 0.f, v1 = 0.f;
#pragma unroll
    for (int i = 0; i < WV; ++i) {
      v0 += ex[i][row][d];
      v1 += ex[i][row][d + 32];
    }
    const int off = ((b * NL + qbase + row) * NH + h) * ND + d;
    outg[off] = v0;
    outg[off + 32] = v1;
  }
}

extern "C" void kernel_launch(void* const* d_in, const int* in_sizes, int n_in,
                              void* d_out, int out_size, void* d_ws, size_t ws_size,
                              hipStream_t stream) {
  const float* q = (const float*)d_in[0];
  const float* k = (const float*)d_in[1];
  const float* v = (const float*)d_in[2];

  const size_t plane = (size_t)NB * NH * ND * NL;  // 3.15M elems, 6.29MB/plane
  __bf16* kp_hi = (__bf16*)d_ws;
  __bf16* kp_lo = kp_hi + plane;
  __bf16* vp_hi = kp_lo + plane;
  __bf16* vp_lo = vp_hi + plane;

  prep<<<NB * 128 * 3, 256, 0, stream>>>(k, v, kp_hi, kp_lo, vp_hi, vp_lo);

  attn_poly<<<NB * NH * (NL / 16), 512, 0, stream>>>(
      q, kp_hi, kp_lo, vp_hi, vp_lo, (float*)d_out);
}

// Round 10
// 266.487 us; speedup vs baseline: 1.0254x; 1.0254x over previous
//
#include <hip/hip_runtime.h>
#include <hip/hip_bf16.h>

#define NB 2
#define NL 2048
#define NH 12
#define ND 64
#define NEWTON 6
#define WV 8            // waves per block (attn)
#define TPW 16          // key-tiles per wave = 128/WV

typedef __bf16 bf16x8 __attribute__((ext_vector_type(8)));
typedef float f32x4 __attribute__((ext_vector_type(4)));
typedef float f32x2 __attribute__((ext_vector_type(2)));

// DPP row_ror reductions within each 16-lane row.
#define ROR_ADD(v, n)                                                         \
  (v) += __int_as_float(__builtin_amdgcn_update_dpp(                          \
      0, __float_as_int(v), 0x120 + (n), 0xF, 0xF, true))
#define ROR_MAX(v, n)                                                         \
  (v) = fmaxf((v), __int_as_float(__builtin_amdgcn_update_dpp(                \
                  0, __float_as_int(v), 0x120 + (n), 0xF, 0xF, true)))

__device__ __forceinline__ void split_bf16(float f, __bf16& hi, __bf16& lo) {
  __bf16 h = (__bf16)f;
  hi = h;
  lo = (__bf16)(f - (float)h);
}

// ---- prep: block = (b, kt16, head-group of 4). 768 blocks, 256 thr, 33 KB LDS.
__global__ __launch_bounds__(256) void prep(
    const float* __restrict__ kg, const float* __restrict__ vg,
    __bf16* __restrict__ kp_hi, __bf16* __restrict__ kp_lo,
    __bf16* __restrict__ vp_hi, __bf16* __restrict__ vp_lo) {
  __shared__ __align__(16) float kv[2][16][260];  // [K/V][key][4 heads x 64 d]
  const int blk = blockIdx.x;
  const int hg = blk % 3;
  const int kt = (blk / 3) & 127;
  const int b = blk / 384;
  const int t = threadIdx.x;
  const int w = t >> 6;           // wave 0..3 == local head
  const int lane = t & 63;
  const int quad = lane >> 4;
  const int l16 = lane & 15;

#pragma unroll
  for (int i = 0; i < 4; ++i) {
    const int f = i * 1024 + t * 4;
    const int key = f >> 8;
    const int rem = f & 255;
    const size_t src =
        (size_t)(b * NL + kt * 16 + key) * (NH * ND) + hg * 256 + rem;
    *(f32x4*)(&kv[0][key][rem]) = *(const f32x4*)(kg + src);
    *(f32x4*)(&kv[1][key][rem]) = *(const f32x4*)(vg + src);
  }
  __syncthreads();

  const int h = hg * 4 + w;

  // ---- K pack ----
  {
    const float* p = &kv[0][l16][w * 64 + quad * 8];
    f32x4 a0 = *(const f32x4*)(p);
    f32x4 a1 = *(const f32x4*)(p + 4);
    f32x4 a2 = *(const f32x4*)(p + 32);
    f32x4 a3 = *(const f32x4*)(p + 36);
    bf16x8 h0, l0, h1, l1;
#pragma unroll
    for (int j = 0; j < 4; ++j) {
      __bf16 hb, lb;
      split_bf16(a0[j], hb, lb); h0[j] = hb;     l0[j] = lb;
      split_bf16(a1[j], hb, lb); h0[4 + j] = hb; l0[4 + j] = lb;
      split_bf16(a2[j], hb, lb); h1[j] = hb;     l1[j] = lb;
      split_bf16(a3[j], hb, lb); h1[4 + j] = hb; l1[4 + j] = lb;
    }
    const size_t basek =
        ((size_t)((b * NH + h) * 128 + kt) * 2) * 512 + lane * 8;
    *(bf16x8*)(kp_hi + basek) = h0;
    *(bf16x8*)(kp_lo + basek) = l0;
    *(bf16x8*)(kp_hi + basek + 512) = h1;
    *(bf16x8*)(kp_lo + basek + 512) = l1;
  }

  // ---- V pack ----
  {
    const int halfsel = (kt >> 3) & 1;
    const int pi = (kt >> 4) * 8 + (kt & 7);
    const int q2 = quad & 1;
    const int nhalf = quad >> 1;
    const int qdst = 2 * halfsel + q2;
#pragma unroll
    for (int nn = 0; nn < 2; ++nn) {
      const int n = nhalf * 2 + nn;
      bf16x8 hv, lv;
#pragma unroll
      for (int j = 0; j < 8; ++j) {
        __bf16 hb, lb;
        split_bf16(kv[1][q2 * 8 + j][w * 64 + n * 16 + l16], hb, lb);
        hv[j] = hb;
        lv[j] = lb;
      }
      const size_t off =
          ((((size_t)(b * NH + h) * 64 + pi) * 4 + n) * 64 + qdst * 16 + l16) * 8;
      *(bf16x8*)(vp_hi + off) = hv;
      *(bf16x8*)(vp_lo + off) = lv;
    }
  }
}

// ---------------- main fused attention-poly kernel ----------------
__launch_bounds__(512, 4)
__global__ void attn_poly(const float* __restrict__ qg,
                          const __bf16* __restrict__ kp_hi,
                          const __bf16* __restrict__ kp_lo,
                          const __bf16* __restrict__ vp_hi,
                          const __bf16* __restrict__ vp_lo,
                          float* __restrict__ outg) {
  __shared__ __align__(16) float ex[WV][16][68];      // phase 6 only
  __shared__ __align__(16) __bf16 wslab[WV][2][16][40];  // phase 5 dbuf slabs
  __shared__ float redmax[WV][17];
  __shared__ f32x2 redq[2][WV][17];

  const int tid = threadIdx.x;
  const int w = tid >> 6;
  const int lane = tid & 63;
  const int quad = lane >> 4;
  const int l16 = lane & 15;

  const int blk = blockIdx.x;
  const int qt = blk & 127;
  const int bh = blk >> 7;
  const int h = bh % NH;
  const int b = bh / NH;
  const int qbase = qt * 16;

  // ---- Q fragments: fp32 * 0.125 -> bf16 hi/lo ----
  bf16x8 qhi0, qlo0, qhi1, qlo1;
  {
    const float* qp = qg + ((b * NL + qbase + l16) * NH + h) * ND + quad * 8;
    f32x4 a0 = *(const f32x4*)(qp);
    f32x4 a1 = *(const f32x4*)(qp + 4);
    f32x4 a2 = *(const f32x4*)(qp + 32);
    f32x4 a3 = *(const f32x4*)(qp + 36);
#pragma unroll
    for (int j = 0; j < 4; ++j) {
      __bf16 hb, lb;
      split_bf16(a0[j] * 0.125f, hb, lb); qhi0[j] = hb;     qlo0[j] = lb;
      split_bf16(a1[j] * 0.125f, hb, lb); qhi0[4 + j] = hb; qlo0[4 + j] = lb;
      split_bf16(a2[j] * 0.125f, hb, lb); qhi1[j] = hb;     qlo1[j] = lb;
      split_bf16(a3[j] * 0.125f, hb, lb); qhi1[4 + j] = hb; qlo1[4 + j] = lb;
    }
  }

  // ---- phase 1: S = (Q/8) Kt ; sc2[t][j] = rows (quad*4+2j, +2j+1), col l16 ----
  f32x2 sc2[TPW][2];   // read-only after this phase
  {
    const __bf16* kbh = kp_hi + (size_t)bh * 131072;
    const __bf16* kbl = kp_lo + (size_t)bh * 131072;
#pragma unroll
    for (int t = 0; t < TPW; ++t) {
      const int ktile = w + WV * t;
      const size_t o = (size_t)ktile * 1024 + lane * 8;
      bf16x8 khi0 = *(const bf16x8*)(kbh + o);
      bf16x8 khi1 = *(const bf16x8*)(kbh + o + 512);
      bf16x8 klo0 = *(const bf16x8*)(kbl + o);
      bf16x8 klo1 = *(const bf16x8*)(kbl + o + 512);
      f32x4 acc = {0.f, 0.f, 0.f, 0.f};
      acc = __builtin_amdgcn_mfma_f32_16x16x32_bf16(qhi0, khi0, acc, 0, 0, 0);
      acc = __builtin_amdgcn_mfma_f32_16x16x32_bf16(qhi1, khi1, acc, 0, 0, 0);
      acc = __builtin_amdgcn_mfma_f32_16x16x32_bf16(qhi0, klo0, acc, 0, 0, 0);
      acc = __builtin_amdgcn_mfma_f32_16x16x32_bf16(qhi1, klo1, acc, 0, 0, 0);
      acc = __builtin_amdgcn_mfma_f32_16x16x32_bf16(qlo0, khi0, acc, 0, 0, 0);
      acc = __builtin_amdgcn_mfma_f32_16x16x32_bf16(qlo1, khi1, acc, 0, 0, 0);
      sc2[t][0] = __builtin_shufflevector(acc, acc, 0, 1);
      sc2[t][1] = __builtin_shufflevector(acc, acc, 2, 3);
    }
  }

  // ---- phase 2: row max -> negc[j] = -c0 pairs (= max + 1) ----
  f32x2 negc[2];
  {
    f32x2 mx2[2] = {sc2[0][0], sc2[0][1]};
#pragma unroll
    for (int t = 1; t < TPW; ++t) {
#pragma unroll
      for (int j = 0; j < 2; ++j) {
        mx2[j].x = fmaxf(mx2[j].x, sc2[t][j].x);
        mx2[j].y = fmaxf(mx2[j].y, sc2[t][j].y);
      }
    }
#pragma unroll
    for (int j = 0; j < 2; ++j) {
      ROR_MAX(mx2[j].x, 8); ROR_MAX(mx2[j].x, 4); ROR_MAX(mx2[j].x, 2); ROR_MAX(mx2[j].x, 1);
      ROR_MAX(mx2[j].y, 8); ROR_MAX(mx2[j].y, 4); ROR_MAX(mx2[j].y, 2); ROR_MAX(mx2[j].y, 1);
    }
    if (l16 < 4) {
      float v = (l16 == 0) ? mx2[0].x : (l16 == 1) ? mx2[0].y
              : (l16 == 2) ? mx2[1].x : mx2[1].y;
      redmax[w][quad * 4 + l16] = v;
    }
    __syncthreads();
#pragma unroll
    for (int r = 0; r < 4; ++r) {
      float m = redmax[l16 & 7][quad * 4 + r];
      ROR_MAX(m, 4); ROR_MAX(m, 2); ROR_MAX(m, 1);
      ((float*)negc)[r] = m + 1.0f;            // -c0 = max + 1
    }
  }

  // ---- phase 3: Newton x6 on c (paired rcp, depth-3 chain; R7 recipe) ----
  for (int it = 0; it < NEWTON; ++it) {
    const int par = it & 1;
    f32x2 ps2[2] = {{0.f, 0.f}, {0.f, 0.f}};
    f32x2 psd2[2] = {{0.f, 0.f}, {0.f, 0.f}};
#pragma unroll
    for (int t = 0; t < TPW; ++t) {
#pragma unroll
      for (int j = 0; j < 2; ++j) {
        f32x2 y = negc[j] - sc2[t][j];         // y >= 1 along Newton path
        float z = __builtin_amdgcn_rcpf(y.x * y.y);
        f32x2 r1 = z * __builtin_shufflevector(y, y, 1, 0);  // (1/y.x, 1/y.y)
        f32x2 r2 = r1 * r1;
        ps2[j] += r2;
        psd2[j] += r2 * r1;
      }
    }
#pragma unroll
    for (int j = 0; j < 2; ++j) {
      ROR_ADD(ps2[j].x, 8);  ROR_ADD(ps2[j].x, 4);  ROR_ADD(ps2[j].x, 2);  ROR_ADD(ps2[j].x, 1);
      ROR_ADD(ps2[j].y, 8);  ROR_ADD(ps2[j].y, 4);  ROR_ADD(ps2[j].y, 2);  ROR_ADD(ps2[j].y, 1);
      ROR_ADD(psd2[j].x, 8); ROR_ADD(psd2[j].x, 4); ROR_ADD(psd2[j].x, 2); ROR_ADD(psd2[j].x, 1);
      ROR_ADD(psd2[j].y, 8); ROR_ADD(psd2[j].y, 4); ROR_ADD(psd2[j].y, 2); ROR_ADD(psd2[j].y, 1);
    }
    if (l16 < 4) {
      float a = (l16 == 0) ? ps2[0].x : (l16 == 1) ? ps2[0].y
              : (l16 == 2) ? ps2[1].x : ps2[1].y;
      float d = (l16 == 0) ? psd2[0].x : (l16 == 1) ? psd2[0].y
              : (l16 == 2) ? psd2[1].x : psd2[1].y;
      redq[par][w][quad * 4 + l16] = f32x2{a, d};
    }
    __syncthreads();
#pragma unroll
    for (int r = 0; r < 4; ++r) {
      f32x2 v = redq[par][l16 & 7][quad * 4 + r];
      ROR_ADD(v.x, 4); ROR_ADD(v.x, 2); ROR_ADD(v.x, 1);
      ROR_ADD(v.y, 4); ROR_ADD(v.y, 2); ROR_ADD(v.y, 1);
      ((float*)negc)[r] +=
          (v.x - 1.0f) * __builtin_amdgcn_rcpf(2.0f * v.y + 1e-8f);
    }
  }

  // ---- phase 5: O = W * (Vhi + Vlo); double-buffered bf16 weight slab ----
  // Weights for p-iter's two tiles are written one iteration AHEAD into the
  // alternate buffer, so the single lgkmcnt wait covers a write whose latency
  // was hidden by the previous iteration's MFMAs/loads.
  f32x4 oacc[4];
#pragma unroll
  for (int n = 0; n < 4; ++n) oacc[n] = (f32x4){0.f, 0.f, 0.f, 0.f};
  const __bf16* vpbh = vp_hi + (size_t)bh * 131072;
  const __bf16* vpbl = vp_lo + (size_t)bh * 131072;

  // prologue: weights for tiles 0,1 -> buf 0
#pragma unroll
  for (int ts = 0; ts < 2; ++ts) {
    f32x2 a = negc[0] - sc2[ts][0];
    f32x2 bb = negc[1] - sc2[ts][1];
    float za = __builtin_amdgcn_rcpf(a.x * a.y);
    float zb = __builtin_amdgcn_rcpf(bb.x * bb.y);
    f32x2 ra = za * __builtin_shufflevector(a, a, 1, 0);
    f32x2 rb = zb * __builtin_shufflevector(bb, bb, 1, 0);
    f32x2 wa = ra * ra;
    f32x2 wb = rb * rb;
    wslab[w][0][quad * 4 + 0][ts * 16 + l16] = (__bf16)wa.x;
    wslab[w][0][quad * 4 + 1][ts * 16 + l16] = (__bf16)wa.y;
    wslab[w][0][quad * 4 + 2][ts * 16 + l16] = (__bf16)wb.x;
    wslab[w][0][quad * 4 + 3][ts * 16 + l16] = (__bf16)wb.y;
  }

#pragma unroll
  for (int p = 0; p < 8; ++p) {
    const size_t vo = ((size_t)(p * 8 + w) * 4) * 512 + lane * 8;
    // V loads (independent of slab) issue first
    bf16x8 bhv0 = *(const bf16x8*)(vpbh + vo);
    bf16x8 bhv1 = *(const bf16x8*)(vpbh + vo + 512);
    bf16x8 bhv2 = *(const bf16x8*)(vpbh + vo + 1024);
    bf16x8 bhv3 = *(const bf16x8*)(vpbh + vo + 1536);
    bf16x8 blv0 = *(const bf16x8*)(vpbl + vo);
    bf16x8 blv1 = *(const bf16x8*)(vpbl + vo + 512);
    bf16x8 blv2 = *(const bf16x8*)(vpbl + vo + 1024);
    bf16x8 blv3 = *(const bf16x8*)(vpbl + vo + 1536);

    asm volatile("s_waitcnt lgkmcnt(0)" ::: "memory");  // slab writes visible
    bf16x8 aw = *(const bf16x8*)(&wslab[w][p & 1][l16][quad * 8]);

    // write NEXT iteration's weights into the other buffer (no wait needed)
    if (p < 7) {
#pragma unroll
      for (int ts = 0; ts < 2; ++ts) {
        const int t = 2 * (p + 1) + ts;
        f32x2 a = negc[0] - sc2[t][0];
        f32x2 bb = negc[1] - sc2[t][1];
        float za = __builtin_amdgcn_rcpf(a.x * a.y);
        float zb = __builtin_amdgcn_rcpf(bb.x * bb.y);
        f32x2 ra = za * __builtin_shufflevector(a, a, 1, 0);
        f32x2 rb = zb * __builtin_shufflevector(bb, bb, 1, 0);
        f32x2 wa = ra * ra;
        f32x2 wb = rb * rb;
        wslab[w][(p + 1) & 1][quad * 4 + 0][ts * 16 + l16] = (__bf16)wa.x;
        wslab[w][(p + 1) & 1][quad * 4 + 1][ts * 16 + l16] = (__bf16)wa.y;
        wslab[w][(p + 1) & 1][quad * 4 + 2][ts * 16 + l16] = (__bf16)wb.x;
        wslab[w][(p + 1) & 1][quad * 4 + 3][ts * 16 + l16] = (__bf16)wb.y;
      }
    }

    oacc[0] = __builtin_amdgcn_mfma_f32_16x16x32_bf16(aw, bhv0, oacc[0], 0, 0, 0);
    oacc[1] = __builtin_amdgcn_mfma_f32_16x16x32_bf16(aw, bhv1, oacc[1], 0, 0, 0);
    oacc[2] = __builtin_amdgcn_mfma_f32_16x16x32_bf16(aw, bhv2, oacc[2], 0, 0, 0);
    oacc[3] = __builtin_amdgcn_mfma_f32_16x16x32_bf16(aw, bhv3, oacc[3], 0, 0, 0);
    oacc[0] = __builtin_amdgcn_mfma_f32_16x16x32_bf16(aw, blv0, oacc[0], 0, 0, 0);
    oacc[1] = __builtin_amdgcn_mfma_f32_16x16x32_bf16(aw, blv1, oacc[1], 0, 0, 0);
    oacc[2] = __builtin_amdgcn_mfma_f32_16x16x32_bf16(aw, blv2, oacc[2], 0, 0, 0);
    oacc[3] = __builtin_amdgcn_mfma_f32_16x16x32_bf16(aw, blv3, oacc[3], 0, 0, 0);
  }

  // ---- phase 6: reduce partials across waves, write global ----
#pragma unroll
  for (int n = 0; n < 4; ++n)
#pragma unroll
    for (int r = 0; r < 4; ++r)
      ex[w][quad * 4 + r][n * 16 + l16] = oacc[n][r];
  __syncthreads();
  {
    const int row = 2 * w + (lane >> 5);
    const int d = lane & 31;
    float v0 = 0.f, v1 = 0.f;
#pragma unroll
    for (int i = 0; i < WV; ++i) {
      v0 += ex[i][row][d];
      v1 += ex[i][row][d + 32];
    }
    const int off = ((b * NL + qbase + row) * NH + h) * ND + d;
    outg[off] = v0;
    outg[off + 32] = v1;
  }
}

extern "C" void kernel_launch(void* const* d_in, const int* in_sizes, int n_in,
                              void* d_out, int out_size, void* d_ws, size_t ws_size,
                              hipStream_t stream) {
  const float* q = (const float*)d_in[0];
  const float* k = (const float*)d_in[1];
  const float* v = (const float*)d_in[2];

  const size_t plane = (size_t)NB * NH * ND * NL;  // 3.15M elems, 6.29MB/plane
  __bf16* kp_hi = (__bf16*)d_ws;
  __bf16* kp_lo = kp_hi + plane;
  __bf16* vp_hi = kp_lo + plane;
  __bf16* vp_lo = vp_hi + plane;

  prep<<<NB * 128 * 3, 256, 0, stream>>>(k, v, kp_hi, kp_lo, vp_hi, vp_lo);

  attn_poly<<<NB * NH * (NL / 16), 512, 0, stream>>>(
      q, kp_hi, kp_lo, vp_hi, vp_lo, (float*)d_out);
}